// Round 5
// baseline (148.563 us; speedup 1.0000x reference)
//
#include <hip/hip_runtime.h>
#include <hip/hip_bf16.h>

// Decoder loss: keep-mask (kth-value threshold + local max), BCE coord loss,
// bidirectional NN recolor + L1 rgb loss.
// L=16384 candidates, N=10000 targets, K=8 (collapses to argmin; R1-proven).
// R13: in-block-complete dual scan. Bwd block owns 32 targets and streams ALL
// kept candidates (8 k-slices x 32 targets = 256 thr); per-target partials
// merge in-block (shfl + 1KB LDS) with the exact-d packed key (R1/R3
// semantics preserved); block epilogue does the color scatter directly.
// Fwd block owns 32 kept cands, finalizes in-block, PLAIN-stores fmin.
// Kills k_scatter dispatch + tmin array/init/atomicMin traffic (14.7MB) +
// fmin atomics/init. 5 -> 4 dispatches. Scan inner loop is R8's proven
// codegen (if(d<best), 1 b128/64 pairs via free 2-way addr split); R8-R10
// measured 43+-1us across 3.5x LDS-ratio and 2x occupancy variation.
// Hard-learned rules for this part:
//   - grid.sync ~40us each (R4), mass __threadfence ~0.1ms+ (R7): NEVER fuse
//     across device-scope ordering. Kernel boundary (~10us) is the cheap sync.
//   - LDS-tiled broadcast scans, not uniform global streams (R5: 7x slower).
//   - bwd & fwd scans are independent -> one dual-role grid, zero sync needed.
//   - fwd scans ALL kept (R7-proven exact); kills k_empty + elist.
//   - per-slice surrogate argmin + cross-slice EXACT-d merge key (R1/R3);
//     do not switch to global surrogate argmin (near-tie winner can flip).
//   - k_scan2 inner loop: duration/pair is invariant to VALU count, LDS
//     count, occupancy (R8-R11). Don't touch without a disasm-level model.

typedef unsigned long long ull;

// ---- helper: pick bin containing rank from LDS hist (wave 0) ---------------
__device__ __forceinline__ void select_bin(
    unsigned int* hist, int nb, unsigned int rank,
    unsigned int* sB, unsigned int* sR, int tid) {
  if (tid < 64) {
    int g = nb >> 6;
    unsigned int sum = 0;
    for (int j = 0; j < g; ++j) sum += hist[tid * g + j];
    unsigned int incl = sum;
    for (int o = 1; o < 64; o <<= 1) {
      unsigned int v = __shfl_up(incl, o);
      if (tid >= o) incl += v;
    }
    unsigned int excl = incl - sum;
    bool cond = (rank >= excl) && (rank < incl);
    unsigned long long bal = __ballot(cond);
    int first = __ffsll((long long)bal) - 1;
    if (tid == first) {
      unsigned int r = rank - excl, cum = 0;
      for (int j = 0; j < g; ++j) {
        unsigned int c = hist[tid * g + j];
        if (r < cum + c) { *sB = (unsigned int)(tid * g + j); *sR = r - cum; break; }
        cum += c;
      }
    }
  }
}

// ---- Kernel 1: fused init + keys + exact rank select -----------------------
// Blocks 0..IB-1: array init (BW-trivial). Block IB: compute monotone keys
// into LDS + islm to global, then 3-sweep radix select entirely from LDS.
// Assumes L <= 16384 (fixed by problem setup).
__global__ __launch_bounds__(512) void k_init_sel(
    const float* __restrict__ pred, const float* __restrict__ txyz,
    const int* __restrict__ pnum_p,
    float4* __restrict__ ttile, float4* __restrict__ numden,
    int* __restrict__ zerohit,
    unsigned char* __restrict__ islm, int* __restrict__ counters,
    float* __restrict__ out, float* __restrict__ thr_out,
    int L, int N, int IB) {
  __shared__ unsigned int skey[16384];
  __shared__ unsigned int hist[2048];
  __shared__ unsigned int sB, sR;
  int tid = threadIdx.x;

  if ((int)blockIdx.x < IB) {
    // ---- init role --------------------------------------------------------
    int gidx = blockIdx.x * 512 + tid;
    int gsz = IB * 512;
    for (int i = gidx; i < N; i += gsz) {
      float x = txyz[3*i], y = txyz[3*i+1], z = txyz[3*i+2];
      ttile[i] = make_float4(x, y, z, fmaf(x, x, fmaf(y, y, z * z)));
    }
    for (int i = gidx; i < L; i += gsz) {
      numden[i] = make_float4(0.f, 0.f, 0.f, 0.f);
      zerohit[i] = 0;
    }
    if (gidx < 8) counters[gidx] = 0;
    if (gidx < 2) out[gidx] = 0.f;
    return;
  }

  // ---- selector role ------------------------------------------------------
  // phase A: monotone keys (LDS) + per-8 local max (global islm)
  int ngroups = L >> 3;
  for (int g = tid; g < ngroups; g += 512) {
    const float4* pv = (const float4*)pred + (size_t)g * 2;
    float4 a = pv[0], b = pv[1];
    float v[8] = {a.x, a.y, a.z, a.w, b.x, b.y, b.z, b.w};
    int bi = 0; float bv = v[0];
    #pragma unroll
    for (int j = 1; j < 8; ++j) if (v[j] > bv) { bv = v[j]; bi = j; }
    ull lmpack = 0ull;
    #pragma unroll
    for (int j = 0; j < 8; ++j) {
      unsigned int fb = __float_as_uint(v[j]);
      unsigned int mk = (fb & 0x80000000u) ? ~fb : (fb | 0x80000000u);
      if (j == bi) { mk = 0xFF800000u; lmpack |= 1ull << (8 * j); }  // +inf
      skey[g * 8 + j] = mk;
    }
    *(ull*)(islm + (size_t)g * 8) = lmpack;
  }
  __syncthreads();

  // phase B: 3-sweep radix select over LDS keys
  unsigned int rank = (unsigned int)(L - pnum_p[0] - 1);
  const uint4* s4 = (const uint4*)skey;
  int n4 = L >> 2;
  for (int b = tid; b < 2048; b += 512) hist[b] = 0u;
  __syncthreads();
  for (int i = tid; i < n4; i += 512) {
    uint4 v = s4[i];
    atomicAdd(&hist[v.x >> 21], 1u); atomicAdd(&hist[v.y >> 21], 1u);
    atomicAdd(&hist[v.z >> 21], 1u); atomicAdd(&hist[v.w >> 21], 1u);
  }
  __syncthreads();
  select_bin(hist, 2048, rank, &sB, &sR, tid);
  __syncthreads();
  unsigned int B1 = sB, R1 = sR;
  for (int b = tid; b < 2048; b += 512) hist[b] = 0u;
  __syncthreads();
  for (int i = tid; i < n4; i += 512) {
    uint4 v = s4[i];
    if ((v.x >> 21) == B1) atomicAdd(&hist[(v.x >> 10) & 2047u], 1u);
    if ((v.y >> 21) == B1) atomicAdd(&hist[(v.y >> 10) & 2047u], 1u);
    if ((v.z >> 21) == B1) atomicAdd(&hist[(v.z >> 10) & 2047u], 1u);
    if ((v.w >> 21) == B1) atomicAdd(&hist[(v.w >> 10) & 2047u], 1u);
  }
  __syncthreads();
  select_bin(hist, 2048, R1, &sB, &sR, tid);
  __syncthreads();
  unsigned int B2 = sB, R2 = sR;
  for (int b = tid; b < 1024; b += 512) hist[b] = 0u;
  __syncthreads();
  unsigned int top22 = (B1 << 11) | B2;
  for (int i = tid; i < n4; i += 512) {
    uint4 v = s4[i];
    if ((v.x >> 10) == top22) atomicAdd(&hist[v.x & 1023u], 1u);
    if ((v.y >> 10) == top22) atomicAdd(&hist[v.y & 1023u], 1u);
    if ((v.z >> 10) == top22) atomicAdd(&hist[v.z & 1023u], 1u);
    if ((v.w >> 10) == top22) atomicAdd(&hist[v.w & 1023u], 1u);
  }
  __syncthreads();
  select_bin(hist, 1024, R2, &sB, &sR, tid);
  __syncthreads();
  if (tid == 0) {
    unsigned int fkey = (B1 << 21) | (B2 << 10) | sB;
    unsigned int fb = (fkey & 0x80000000u) ? (fkey & 0x7FFFFFFFu) : ~fkey;
    thr_out[0] = __uint_as_float(fb);
  }
}

// ---- Kernel 2: keep mask + compaction + BCE reduce -------------------------
__global__ __launch_bounds__(256) void k_keepc(
    const float* __restrict__ pred, const unsigned char* __restrict__ islm,
    const float* __restrict__ thr_p, const float* __restrict__ cxyz,
    const int* __restrict__ ktgt, int* __restrict__ keep,
    float4* __restrict__ klist, int* __restrict__ kidx,
    int* __restrict__ counters, float* __restrict__ out, int L) {
  int i = blockIdx.x * 256 + threadIdx.x;
  float thr = thr_p[0];
  float term = 0.f;
  if (i < L) {
    float p = pred[i];
    bool kp = (p > thr) || islm[i];
    keep[i] = kp ? 1 : 0;
    if (kp) {
      int pos = atomicAdd(&counters[0], 1);   // order irrelevant (no ties)
      float x = cxyz[3*i], y = cxyz[3*i+1], z = cxyz[3*i+2];
      klist[pos] = make_float4(x, y, z, fmaf(x, x, fmaf(y, y, z * z)));
      kidx[pos] = i;
    }
    float t = (float)ktgt[i];
    term = fmaxf(p, 0.f) - p * t + log1pf(expf(-fabsf(p)));
  }
  for (int o = 32; o > 0; o >>= 1) term += __shfl_down(term, o);
  if ((threadIdx.x & 63) == 0) atomicAdd(&out[0], term);
}

// ---- Kernel 3: dual-role in-block-complete scan ----------------------------
// bwd block: 32 targets x 8 k-slices; streams all kept thru 256-elem LDS
// tiles; in-block exact-d merge; epilogue scatters colors directly.
// fwd block: 32 kept cands x 8 t-slices; plain-store fmin (unique per cand).
__global__ __launch_bounds__(256) void k_scan2(
    const float* __restrict__ txyz, const float* __restrict__ trgb,
    const float4* __restrict__ klist, const int* __restrict__ kidx,
    const float4* __restrict__ ttile, const int* __restrict__ counters,
    float4* __restrict__ numden, int* __restrict__ zerohit,
    float4* __restrict__ zcolor, ull* __restrict__ fmin,
    int L, int N, int BB) {
  __shared__ float4 tile[256];
  __shared__ ull red[4][32];
  int tid = threadIdx.x, bx = blockIdx.x;
  int kc = counters[0];
  int lane = tid & 63, wv = tid >> 6;
  int tgt = tid & 31;
  int lo = (tid >> 5) * 32;   // slice range within tile

  if (bx < BB) {
    // ---- backward: targets T0..T0+31 vs ALL kept --------------------------
    int T0 = bx * 32;
    int t = T0 + tgt;
    bool act = t < N;
    float tx = 0.f, ty = 0.f, tz = 0.f;
    if (act) { tx = txyz[3*t]; ty = txyz[3*t+1]; tz = txyz[3*t+2]; }
    float ntx = -2.f * tx, nty = -2.f * ty, ntz = -2.f * tz;
    float best = 3e38f; int bpos = -1;
    for (int tb = 0; tb < kc; tb += 256) {
      int cnt = min(256, kc - tb);
      if (tid < cnt) tile[tid] = klist[tb + tid];
      __syncthreads();
      int hi = min(lo + 32, cnt);
      #pragma unroll 4
      for (int c = lo; c < hi; ++c) {
        float4 cd = tile[c];
        // monotone surrogate |c|^2 - 2 t.c (argmin-equiv to |t-c|^2)
        float d = fmaf(ntx, cd.x, cd.w);
        d = fmaf(nty, cd.y, d);
        d = fmaf(ntz, cd.z, d);
        if (d < best) { best = d; bpos = tb + c; }
      }
      __syncthreads();
    }
    ull pack = ~0ull;
    if (act && bpos >= 0) {
      float4 cd = klist[bpos];
      float dx = tx - cd.x, dy = ty - cd.y, dz = tz - cd.z;
      float dtrue = fmaf(dx, dx, fmaf(dy, dy, dz * dz));  // exact (R1)
      pack = ((ull)__float_as_uint(dtrue) << 32) | (unsigned int)kidx[bpos];
    }
    ull o = __shfl_down(pack, 32);
    pack = (o < pack) ? o : pack;
    if (lane < 32) red[wv][lane] = pack;
    __syncthreads();
    if (wv == 0 && lane < 32 && act) {
      ull m = red[0][lane];
      ull m1 = red[1][lane]; m = (m1 < m) ? m1 : m;
      ull m2 = red[2][lane]; m = (m2 < m) ? m2 : m;
      ull m3 = red[3][lane]; m = (m3 < m) ? m3 : m;
      // fused scatter (was k_scatter)
      float d = __uint_as_float((unsigned int)(m >> 32));
      int idx = (int)(m & 0xFFFFFFFFull);
      float r = trgb[3*t], g = trgb[3*t+1], b = trgb[3*t+2];
      if (d == 0.0f) {
        zerohit[idx] = 1;
        zcolor[idx] = make_float4(r, g, b, 0.f);
      } else {
        float w = 1.0f / sqrtf(fmaxf(d, 1e-30f));
        atomicAdd(&numden[idx].x, r * w);
        atomicAdd(&numden[idx].y, g * w);
        atomicAdd(&numden[idx].z, b * w);
        atomicAdd(&numden[idx].w, w);
      }
    }
  } else {
    // ---- forward: kept cands C0..C0+31 vs ALL targets ---------------------
    int C0 = (bx - BB) * 32;
    if (C0 >= kc) return;   // uniform early-exit
    int e = C0 + tgt;
    bool act = e < kc;
    float ncx = 0.f, ncy = 0.f, ncz = 0.f, c2 = 0.f;
    int li = 0;
    if (act) {
      float4 cd = klist[e];
      ncx = -2.f * cd.x; ncy = -2.f * cd.y; ncz = -2.f * cd.z;
      c2 = cd.w; li = kidx[e];
    }
    float best = 3e38f; int bpos = -1;
    for (int tb = 0; tb < N; tb += 256) {
      int cnt = min(256, N - tb);
      if (tid < cnt) tile[tid] = ttile[tb + tid];
      __syncthreads();
      int hi = min(lo + 32, cnt);
      #pragma unroll 4
      for (int c = lo; c < hi; ++c) {
        float4 td = tile[c];
        float d = fmaf(ncx, td.x, td.w);
        d = fmaf(ncy, td.y, d);
        d = fmaf(ncz, td.z, d);
        if (d < best) { best = d; bpos = tb + c; }
      }
      __syncthreads();
    }
    ull pack = ~0ull;
    if (act && bpos >= 0) {
      float dkey = fmaxf(best + c2, 0.f);       // consistent merge key (R3)
      pack = ((ull)__float_as_uint(dkey) << 32) | (unsigned int)bpos;
    }
    ull o = __shfl_down(pack, 32);
    pack = (o < pack) ? o : pack;
    if (lane < 32) red[wv][lane] = pack;
    __syncthreads();
    if (wv == 0 && lane < 32 && act) {
      ull m = red[0][lane];
      ull m1 = red[1][lane]; m = (m1 < m) ? m1 : m;
      ull m2 = red[2][lane]; m = (m2 < m) ? m2 : m;
      ull m3 = red[3][lane]; m = (m3 < m) ? m3 : m;
      fmin[li] = m;   // plain store: unique per kept candidate
    }
  }
}

// ---- Kernel 4: final recolor select + L1 reduce ----------------------------
__global__ __launch_bounds__(256) void k_loss(
    const float* __restrict__ crgb, const float* __restrict__ trgb,
    const int* __restrict__ keep, const float4* __restrict__ numden,
    const int* __restrict__ zerohit, const float4* __restrict__ zcolor,
    const ull* __restrict__ fmin, float* __restrict__ out, int L) {
  int l = blockIdx.x * 256 + threadIdx.x;
  float loss = 0.f;
  if (l < L && keep[l]) {
    float rr, rg, rb;
    if (zerohit[l]) {
      float4 z = zcolor[l]; rr = z.x; rg = z.y; rb = z.z;
    } else {
      float4 nd = numden[l];
      if (nd.w != 0.f) { rr = nd.x / nd.w; rg = nd.y / nd.w; rb = nd.z / nd.w; }
      else {
        int ti = (int)(fmin[l] & 0xFFFFFFFFull);
        rr = trgb[3*ti]; rg = trgb[3*ti+1]; rb = trgb[3*ti+2];
      }
    }
    float sr = crgb[3*l]*255.f, sg = crgb[3*l+1]*255.f, sb = crgb[3*l+2]*255.f;
    loss = fabsf(sr - rr) + fabsf(sg - rg) + fabsf(sb - rb);
  }
  for (int o = 32; o > 0; o >>= 1) loss += __shfl_down(loss, o);
  if ((threadIdx.x & 63) == 0) atomicAdd(&out[1], loss);
}

extern "C" void kernel_launch(void* const* d_in, const int* in_sizes, int n_in,
                              void* d_out, int out_size, void* d_ws, size_t ws_size,
                              hipStream_t stream) {
  const float* pred = (const float*)d_in[0];
  const float* cxyz = (const float*)d_in[1];
  const float* crgb = (const float*)d_in[2];
  const float* txyz = (const float*)d_in[3];
  const float* trgb = (const float*)d_in[4];
  const int*   ktgt = (const int*)d_in[5];
  const int*   pnum = (const int*)d_in[6];
  int L = in_sizes[0];
  int N = in_sizes[3] / 3;

  // workspace layout: 16B arrays first, then 8B, 4B, bytes
  char* ws = (char*)d_ws;
  size_t off = 0;
  float4* klist  = (float4*)(ws + off);   off += (size_t)L * 16;
  float4* ttile  = (float4*)(ws + off);   off += (size_t)((N + 3) & ~3) * 16;
  float4* numden = (float4*)(ws + off);   off += (size_t)L * 16;
  float4* zcolor = (float4*)(ws + off);   off += (size_t)L * 16;
  ull* fmin      = (ull*)(ws + off);      off += (size_t)L * 8;
  int* keep      = (int*)(ws + off);      off += (size_t)L * 4;
  int* kidx      = (int*)(ws + off);      off += (size_t)L * 4;
  int* zerohit   = (int*)(ws + off);      off += (size_t)L * 4;
  float* thr_slot = (float*)(ws + off);   off += 16;
  int* counters  = (int*)(ws + off);      off += 256;   // [0]=kcount
  unsigned char* islm = (unsigned char*)(ws + off); off += ((size_t)L + 15) & ~15ull;
  float* out = (float*)d_out;

  int nbL = (L + 255) / 256;   // 64
  int mx = max(L, N);

  // Kernel 1: fused init + keys + select. Blocks 0..IB-1 init, block IB sels.
  int IB = (mx + 511) / 512;   // 32
  k_init_sel<<<IB + 1, 512, 0, stream>>>(
      pred, txyz, pnum, ttile, numden, zerohit, islm, counters,
      out, thr_slot, L, N, IB);

  k_keepc<<<nbL, 256, 0, stream>>>(
      pred, islm, thr_slot, cxyz, ktgt, keep, klist, kidx, counters, out, L);

  // Kernel 3: dual-role in-block-complete scan + fused scatter.
  int BB = (N + 31) / 32;      // 313 bwd blocks
  int BF = (L + 31) / 32;      // 512 fwd blocks (early-exit trims to kc/32)
  k_scan2<<<BB + BF, 256, 0, stream>>>(
      txyz, trgb, klist, kidx, ttile, counters, numden, zerohit, zcolor,
      fmin, L, N, BB);

  k_loss<<<nbL, 256, 0, stream>>>(
      crgb, trgb, keep, numden, zerohit, zcolor, fmin, out, L);
}

// Round 7
// 132.125 us; speedup vs baseline: 1.1244x; 1.1244x over previous
//
#include <hip/hip_runtime.h>
#include <hip/hip_bf16.h>

// Decoder loss: keep-mask (kth-value threshold + local max), BCE coord loss,
// bidirectional NN recolor + L1 rgb loss.
// L=16384 candidates, N=10000 targets, K=8 (collapses to argmin; R1-proven).
// R14 (resubmit; R6 bench was a broker GPUAcquisitionTimeout, no data):
// R12 base (132.4us best) + keepc folded into kernel-1 via a
// 17-co-resident-block release/acquire handshake (selector computes thr,
// release-stores flag; init blocks acquire-spin then do keep/compact/BCE).
// Flag reset by a 4B hipMemsetAsync (workspace persists across launches).
// R13 lesson: in-block-complete scan regressed 62us - 32 c-steps between
// barriers + 19% occ; scan2 needs >=128 c-steps per barrier pair.
// Hard-learned rules for this part:
//   - grid.sync ~40us each (R4), mass __threadfence ~0.1ms+ (R7): NEVER fuse
//     across device-scope ordering at scale. Tiny co-resident handshakes
//     (17 blocks, one release/acquire) are the exception. Kernel boundary
//     (~6-8us) is otherwise the cheap sync.
//   - LDS-tiled broadcast scans, not uniform global streams (R5: 7x slower).
//   - bwd & fwd scans are independent -> one dual-role grid, zero sync needed.
//   - fwd scans ALL kept (R7-proven exact); kills k_empty + elist.
//   - per-chunk surrogate argmin + cross-chunk EXACT-d merge key (R1/R3);
//     do not switch to global surrogate argmin (near-tie winner can flip).
//   - k_scan2 inner loop: duration/pair invariant to VALU count, LDS count,
//     occupancy (R8-R11) at ~0.165 cyc/pair. Don't touch without disasm.

#define SCAN_T 256   // threads per block (scan)
#define CHUNK  128   // tile elements per y-chunk
typedef unsigned long long ull;

// ---- helper: pick bin containing rank from LDS hist (wave 0) ---------------
__device__ __forceinline__ void select_bin(
    unsigned int* hist, int nb, unsigned int rank,
    unsigned int* sB, unsigned int* sR, int tid) {
  if (tid < 64) {
    int g = nb >> 6;
    unsigned int sum = 0;
    for (int j = 0; j < g; ++j) sum += hist[tid * g + j];
    unsigned int incl = sum;
    for (int o = 1; o < 64; o <<= 1) {
      unsigned int v = __shfl_up(incl, o);
      if (tid >= o) incl += v;
    }
    unsigned int excl = incl - sum;
    bool cond = (rank >= excl) && (rank < incl);
    unsigned long long bal = __ballot(cond);
    int first = __ffsll((long long)bal) - 1;
    if (tid == first) {
      unsigned int r = rank - excl, cum = 0;
      for (int j = 0; j < g; ++j) {
        unsigned int c = hist[tid * g + j];
        if (r < cum + c) { *sB = (unsigned int)(tid * g + j); *sR = r - cum; break; }
        cum += c;
      }
    }
  }
}

// ---- Kernel 1: fused init + keys + select + keep/compact/BCE ---------------
// Blocks 0..IB-1: array init, then acquire-spin on counters[15], then the
// old k_keepc role (keep mask, klist compaction, BCE reduce).
// Block IB (selector): monotone keys into LDS + islm, 3-sweep radix select,
// writes thr + zeroes accumulators, release-stores counters[15]=1.
// All IB+1 = 17 blocks co-resident (<= 256 CUs) -> no deadlock; selector
// never waits on init blocks. AGENT-scope atomics for cross-XCD visibility.
__global__ __launch_bounds__(1024) void k_init_sel(
    const float* __restrict__ pred, const float* __restrict__ txyz,
    const float* __restrict__ cxyz, const int* __restrict__ ktgt,
    const int* __restrict__ pnum_p,
    float4* __restrict__ ttile, float4* __restrict__ numden,
    int* __restrict__ zerohit, ull* __restrict__ tmin, ull* __restrict__ fmin,
    unsigned char* __restrict__ islm, int* __restrict__ keep,
    float4* __restrict__ klist, int* __restrict__ kidx,
    int* counters, float* __restrict__ out, float* __restrict__ thr_out,
    int L, int N, int IB) {
  __shared__ unsigned int skey[16384];
  __shared__ unsigned int hist[2048];
  __shared__ unsigned int sB, sR;
  __shared__ float s_thr;
  int tid = threadIdx.x;

  if ((int)blockIdx.x < IB) {
    // ---- init role --------------------------------------------------------
    int gidx = blockIdx.x * 1024 + tid;
    int gsz = IB * 1024;
    for (int i = gidx; i < N; i += gsz) {
      float x = txyz[3*i], y = txyz[3*i+1], z = txyz[3*i+2];
      ttile[i] = make_float4(x, y, z, fmaf(x, x, fmaf(y, y, z * z)));
      tmin[i] = ~0ull;
    }
    for (int i = gidx; i < L; i += gsz) {
      numden[i] = make_float4(0.f, 0.f, 0.f, 0.f);
      zerohit[i] = 0;
      fmin[i] = ~0ull;
    }
    // ---- handshake: wait for selector's thr (release/acquire, AGENT) ------
    if (tid == 0) {
      while (__hip_atomic_load(&counters[15], __ATOMIC_ACQUIRE,
                               __HIP_MEMORY_SCOPE_AGENT) == 0)
        __builtin_amdgcn_s_sleep(8);
      s_thr = thr_out[0];
    }
    __syncthreads();
    float thr = s_thr;
    // ---- keepc role (was kernel 2): keep mask + compaction + BCE ----------
    // wave = 64 consecutive i -> identical atomicAdd grouping to R12 keepc.
    float term = 0.f;
    for (int i = gidx; i < L; i += gsz) {
      float p = pred[i];
      bool kp = (p > thr) || islm[i];
      keep[i] = kp ? 1 : 0;
      if (kp) {
        int pos = atomicAdd(&counters[0], 1);   // order irrelevant (no ties)
        float x = cxyz[3*i], y = cxyz[3*i+1], z = cxyz[3*i+2];
        klist[pos] = make_float4(x, y, z, fmaf(x, x, fmaf(y, y, z * z)));
        kidx[pos] = i;
      }
      float t = (float)ktgt[i];
      term += fmaxf(p, 0.f) - p * t + log1pf(expf(-fabsf(p)));
    }
    for (int o = 32; o > 0; o >>= 1) term += __shfl_down(term, o);
    if ((tid & 63) == 0) atomicAdd(&out[0], term);
    return;
  }

  // ---- selector role ------------------------------------------------------
  // phase A: monotone keys (LDS) + per-8 local max (global islm)
  int ngroups = L >> 3;
  for (int g = tid; g < ngroups; g += 1024) {
    const float4* pv = (const float4*)pred + (size_t)g * 2;
    float4 a = pv[0], b = pv[1];
    float v[8] = {a.x, a.y, a.z, a.w, b.x, b.y, b.z, b.w};
    int bi = 0; float bv = v[0];
    #pragma unroll
    for (int j = 1; j < 8; ++j) if (v[j] > bv) { bv = v[j]; bi = j; }
    ull lmpack = 0ull;
    #pragma unroll
    for (int j = 0; j < 8; ++j) {
      unsigned int fb = __float_as_uint(v[j]);
      unsigned int mk = (fb & 0x80000000u) ? ~fb : (fb | 0x80000000u);
      if (j == bi) { mk = 0xFF800000u; lmpack |= 1ull << (8 * j); }  // +inf
      skey[g * 8 + j] = mk;
    }
    *(ull*)(islm + (size_t)g * 8) = lmpack;
  }
  __syncthreads();

  // phase B: 3-sweep radix select over LDS keys
  unsigned int rank = (unsigned int)(L - pnum_p[0] - 1);
  const uint4* s4 = (const uint4*)skey;
  int n4 = L >> 2;
  for (int b = tid; b < 2048; b += 1024) hist[b] = 0u;
  __syncthreads();
  for (int i = tid; i < n4; i += 1024) {
    uint4 v = s4[i];
    atomicAdd(&hist[v.x >> 21], 1u); atomicAdd(&hist[v.y >> 21], 1u);
    atomicAdd(&hist[v.z >> 21], 1u); atomicAdd(&hist[v.w >> 21], 1u);
  }
  __syncthreads();
  select_bin(hist, 2048, rank, &sB, &sR, tid);
  __syncthreads();
  unsigned int B1 = sB, R1 = sR;
  for (int b = tid; b < 2048; b += 1024) hist[b] = 0u;
  __syncthreads();
  for (int i = tid; i < n4; i += 1024) {
    uint4 v = s4[i];
    if ((v.x >> 21) == B1) atomicAdd(&hist[(v.x >> 10) & 2047u], 1u);
    if ((v.y >> 21) == B1) atomicAdd(&hist[(v.y >> 10) & 2047u], 1u);
    if ((v.z >> 21) == B1) atomicAdd(&hist[(v.z >> 10) & 2047u], 1u);
    if ((v.w >> 21) == B1) atomicAdd(&hist[(v.w >> 10) & 2047u], 1u);
  }
  __syncthreads();
  select_bin(hist, 2048, R1, &sB, &sR, tid);
  __syncthreads();
  unsigned int B2 = sB, R2 = sR;
  for (int b = tid; b < 1024; b += 1024) hist[b] = 0u;
  __syncthreads();
  unsigned int top22 = (B1 << 11) | B2;
  for (int i = tid; i < n4; i += 1024) {
    uint4 v = s4[i];
    if ((v.x >> 10) == top22) atomicAdd(&hist[v.x & 1023u], 1u);
    if ((v.y >> 10) == top22) atomicAdd(&hist[v.y & 1023u], 1u);
    if ((v.z >> 10) == top22) atomicAdd(&hist[v.z & 1023u], 1u);
    if ((v.w >> 10) == top22) atomicAdd(&hist[v.w & 1023u], 1u);
  }
  __syncthreads();
  select_bin(hist, 1024, R2, &sB, &sR, tid);
  __syncthreads();
  if (tid == 0) {
    unsigned int fkey = (B1 << 21) | (B2 << 10) | sB;
    unsigned int fb = (fkey & 0x80000000u) ? (fkey & 0x7FFFFFFFu) : ~fkey;
    thr_out[0] = __uint_as_float(fb);
    out[0] = 0.f; out[1] = 0.f;       // accumulators zeroed BEFORE release
    #pragma unroll
    for (int c = 0; c < 8; ++c) counters[c] = 0;
  }
  __syncthreads();   // islm + thr + zeroes happen-before the release store
  if (tid == 0)
    __hip_atomic_store(&counters[15], 1, __ATOMIC_RELEASE,
                       __HIP_MEMORY_SCOPE_AGENT);
}

// ---- Kernel 2: dual-role scan (bwd y<YB, fwd y>=YB), LDS-tiled -------------
// R10 body (proven 42-43us): 4 outputs/thread, CHUNK=128, ~1420 active blocks.
__global__ __launch_bounds__(SCAN_T) void k_scan2(
    const float* __restrict__ txyz, const float4* __restrict__ klist,
    const int* __restrict__ kidx, const float4* __restrict__ ttile,
    const int* __restrict__ counters, ull* __restrict__ tmin,
    ull* __restrict__ fmin, int L, int N, int YB) {
  __shared__ float4 tile[CHUNK];
  int tid = threadIdx.x, x = blockIdx.x, y = blockIdx.y;
  int kc = counters[0];

  if (y < YB) {
    // ---- backward: targets x*1024.. (4/thread) vs kept chunk y (128) ------
    int c0 = y * CHUNK;
    if (x * 1024 >= N || c0 >= kc) return;   // uniform early-exit
    int cnt = min(CHUNK, kc - c0);
    if (tid < cnt) tile[tid] = klist[c0 + tid];
    __syncthreads();
    int tb = x * 1024 + tid;
    float ntx[4], nty[4], ntz[4], best[4];
    int bpos[4];
    bool act[4];
    #pragma unroll
    for (int j = 0; j < 4; ++j) {
      int t = tb + 256 * j;
      act[j] = t < N;
      float tx = 0.f, ty = 0.f, tz = 0.f;
      if (act[j]) { tx = txyz[3*t]; ty = txyz[3*t+1]; tz = txyz[3*t+2]; }
      ntx[j] = -2.f * tx; nty[j] = -2.f * ty; ntz[j] = -2.f * tz;
      best[j] = 3e38f; bpos[j] = 0;
    }
    #pragma unroll 4
    for (int c = 0; c < cnt; ++c) {
      float4 cd = tile[c];
      #pragma unroll
      for (int j = 0; j < 4; ++j) {
        // monotone surrogate |c|^2 - 2 t.c (argmin-equiv to |t-c|^2)
        float d = fmaf(ntx[j], cd.x, cd.w);
        d = fmaf(nty[j], cd.y, d);
        d = fmaf(ntz[j], cd.z, d);
        if (d < best[j]) { best[j] = d; bpos[j] = c; }
      }
    }
    #pragma unroll
    for (int j = 0; j < 4; ++j) {
      if (act[j]) {
        int p = c0 + bpos[j];
        float4 cd = klist[p];
        float tx = -0.5f * ntx[j], ty = -0.5f * nty[j], tz = -0.5f * ntz[j];
        float dx = tx - cd.x, dy = ty - cd.y, dz = tz - cd.z;
        float dtrue = fmaf(dx, dx, fmaf(dy, dy, dz * dz));  // exact (R1)
        ull pack = ((ull)__float_as_uint(dtrue) << 32) | (unsigned int)kidx[p];
        atomicMin(&tmin[tb + 256 * j], pack);
      }
    }
  } else {
    // ---- forward: kept cands x*1024.. (4/thread) vs target chunk (128) ----
    int t0 = (y - YB) * CHUNK;
    if (x * 1024 >= kc || t0 >= N) return;   // uniform early-exit
    int tcnt = min(CHUNK, N - t0);
    if (tid < tcnt) tile[tid] = ttile[t0 + tid];
    __syncthreads();
    int eb = x * 1024 + tid;
    float ncx[4], ncy[4], ncz[4], c2[4], best[4];
    int bpos[4], li[4];
    bool act[4];
    #pragma unroll
    for (int j = 0; j < 4; ++j) {
      int e = eb + 256 * j;
      act[j] = e < kc;
      float cx = 0.f, cy = 0.f, cz = 0.f;
      c2[j] = 0.f; li[j] = 0;
      if (act[j]) {
        float4 cd = klist[e];
        cx = cd.x; cy = cd.y; cz = cd.z; c2[j] = cd.w;
        li[j] = kidx[e];
      }
      ncx[j] = -2.f * cx; ncy[j] = -2.f * cy; ncz[j] = -2.f * cz;
      best[j] = 3e38f; bpos[j] = 0;
    }
    #pragma unroll 4
    for (int c = 0; c < tcnt; ++c) {
      float4 td = tile[c];
      #pragma unroll
      for (int j = 0; j < 4; ++j) {
        float d = fmaf(ncx[j], td.x, td.w);
        d = fmaf(ncy[j], td.y, d);
        d = fmaf(ncz[j], td.z, d);
        if (d < best[j]) { best[j] = d; bpos[j] = c; }
      }
    }
    #pragma unroll
    for (int j = 0; j < 4; ++j) {
      if (act[j]) {
        float dkey = fmaxf(best[j] + c2[j], 0.f);  // consistent merge key (R3)
        ull pack = ((ull)__float_as_uint(dkey) << 32) |
                   (unsigned int)(t0 + bpos[j]);
        atomicMin(&fmin[li[j]], pack);
      }
    }
  }
}

// ---- Kernel 3: scatter weighted colors into num/den ------------------------
__global__ __launch_bounds__(256) void k_scatter(
    const float* __restrict__ trgb, const ull* __restrict__ tmin,
    float4* __restrict__ numden, int* __restrict__ zerohit,
    float4* __restrict__ zcolor, int N) {
  int t = blockIdx.x * 256 + threadIdx.x;
  if (t >= N) return;
  ull pack = tmin[t];
  float d = __uint_as_float((unsigned int)(pack >> 32));
  int idx = (int)(pack & 0xFFFFFFFFull);
  float r = trgb[3*t], g = trgb[3*t+1], b = trgb[3*t+2];
  if (d == 0.0f) {
    zerohit[idx] = 1;
    zcolor[idx] = make_float4(r, g, b, 0.f);
  } else {
    float w = 1.0f / sqrtf(fmaxf(d, 1e-30f));
    atomicAdd(&numden[idx].x, r * w);
    atomicAdd(&numden[idx].y, g * w);
    atomicAdd(&numden[idx].z, b * w);
    atomicAdd(&numden[idx].w, w);
  }
}

// ---- Kernel 4: final recolor select + L1 reduce ----------------------------
__global__ __launch_bounds__(256) void k_loss(
    const float* __restrict__ crgb, const float* __restrict__ trgb,
    const int* __restrict__ keep, const float4* __restrict__ numden,
    const int* __restrict__ zerohit, const float4* __restrict__ zcolor,
    const ull* __restrict__ fmin, float* __restrict__ out, int L) {
  int l = blockIdx.x * 256 + threadIdx.x;
  float loss = 0.f;
  if (l < L && keep[l]) {
    float rr, rg, rb;
    if (zerohit[l]) {
      float4 z = zcolor[l]; rr = z.x; rg = z.y; rb = z.z;
    } else {
      float4 nd = numden[l];
      if (nd.w != 0.f) { rr = nd.x / nd.w; rg = nd.y / nd.w; rb = nd.z / nd.w; }
      else {
        int ti = (int)(fmin[l] & 0xFFFFFFFFull);
        rr = trgb[3*ti]; rg = trgb[3*ti+1]; rb = trgb[3*ti+2];
      }
    }
    float sr = crgb[3*l]*255.f, sg = crgb[3*l+1]*255.f, sb = crgb[3*l+2]*255.f;
    loss = fabsf(sr - rr) + fabsf(sg - rg) + fabsf(sb - rb);
  }
  for (int o = 32; o > 0; o >>= 1) loss += __shfl_down(loss, o);
  if ((threadIdx.x & 63) == 0) atomicAdd(&out[1], loss);
}

extern "C" void kernel_launch(void* const* d_in, const int* in_sizes, int n_in,
                              void* d_out, int out_size, void* d_ws, size_t ws_size,
                              hipStream_t stream) {
  const float* pred = (const float*)d_in[0];
  const float* cxyz = (const float*)d_in[1];
  const float* crgb = (const float*)d_in[2];
  const float* txyz = (const float*)d_in[3];
  const float* trgb = (const float*)d_in[4];
  const int*   ktgt = (const int*)d_in[5];
  const int*   pnum = (const int*)d_in[6];
  int L = in_sizes[0];
  int N = in_sizes[3] / 3;

  // workspace layout: 16B arrays first, then 8B, 4B, bytes
  char* ws = (char*)d_ws;
  size_t off = 0;
  float4* klist  = (float4*)(ws + off);   off += (size_t)L * 16;
  float4* ttile  = (float4*)(ws + off);   off += (size_t)((N + 3) & ~3) * 16;
  float4* numden = (float4*)(ws + off);   off += (size_t)L * 16;
  float4* zcolor = (float4*)(ws + off);   off += (size_t)L * 16;
  ull* tmin      = (ull*)(ws + off);      off += (size_t)((N + 1) & ~1) * 8;
  ull* fmin      = (ull*)(ws + off);      off += (size_t)L * 8;
  int* keep      = (int*)(ws + off);      off += (size_t)L * 4;
  int* kidx      = (int*)(ws + off);      off += (size_t)L * 4;
  int* zerohit   = (int*)(ws + off);      off += (size_t)L * 4;
  float* thr_slot = (float*)(ws + off);   off += 16;
  int* counters  = (int*)(ws + off);      off += 256;   // [0]=kcount [15]=flag
  unsigned char* islm = (unsigned char*)(ws + off); off += ((size_t)L + 15) & ~15ull;
  float* out = (float*)d_out;

  int nbL = (L + 255) / 256;   // 64
  int nbN = (N + 255) / 256;   // 40
  int mx = max(L, N);

  // Reset the handshake flag (workspace persists across launches; async
  // memset is graph-capture-safe and the only per-launch state we need).
  hipMemsetAsync((void*)(counters + 15), 0, 4, stream);

  // Kernel 1: fused init + keys + select + keep/compact/BCE.
  int IB = (mx + 1023) / 1024;   // 16 init blocks + 1 selector block
  k_init_sel<<<IB + 1, 1024, 0, stream>>>(
      pred, txyz, cxyz, ktgt, pnum, ttile, numden, zerohit, tmin, fmin,
      islm, keep, klist, kidx, counters, out, thr_slot, L, N, IB);

  // Kernel 2: dual-role scan. x covers 1024 outputs/block; y = 128-chunks.
  int gx = (mx + 1023) / 1024;               // 16
  int YB = (L + CHUNK - 1) / CHUNK;          // 128 kept-chunks (exit at kc)
  int YF = (N + CHUNK - 1) / CHUNK;          // 79 target-chunks
  dim3 gs(gx, YB + YF);
  k_scan2<<<gs, SCAN_T, 0, stream>>>(
      txyz, klist, kidx, ttile, counters, tmin, fmin, L, N, YB);

  k_scatter<<<nbN, 256, 0, stream>>>(trgb, tmin, numden, zerohit, zcolor, N);

  k_loss<<<nbL, 256, 0, stream>>>(
      crgb, trgb, keep, numden, zerohit, zcolor, fmin, out, L);
}